// Round 21
// baseline (1606.326 us; speedup 1.0000x reference)
//
#include <hip/hip_runtime.h>

// f32 accumulate; bf16 MFMA inputs. One fused kernel per layer (weights L2-hot).
// R21 = R20 schedule + R8 48-row geometry: 4 bn/block, 256 thr / 4 waves, NTW=2,
// 3 M-tiles (48 rows, no padding). Halves per-CU L2 weight traffic vs 2 bn/block.
// Tiles 48x128 bf16 = 12 KB; LDS = 5*12288 + 256 = 61696 B => 2 blocks/CU.
// h/enc bf16 in ws; lnbuf aliased into P2. __launch_bounds__(256,2) => VGPR cap 128.

#define B_   64
#define S_   12
#define N_   170
#define BN_  (B_*N_)      // 10880
#define E_   128
#define L_   4
#define C_   2
#define H_   8
#define DH_  16
#define FF_  512
#define EPS_ 1e-5f
#define THREADS 256

typedef unsigned short u16;
typedef __attribute__((ext_vector_type(4))) float f32x4;
typedef __attribute__((ext_vector_type(8))) u16   us8;
typedef __attribute__((ext_vector_type(4))) u16   us4;
typedef __attribute__((ext_vector_type(8))) __bf16 bf16x8;
union FragU { us8 u; bf16x8 b; };

__device__ __forceinline__ u16 f2bf(float f) {
    __bf16 h = (__bf16)f;
    return __builtin_bit_cast(u16, h);
}
__device__ __forceinline__ float bf2f(u16 s) {
    return __builtin_bit_cast(float, (unsigned)s << 16);
}

// ---------------- enc_x f32 -> bf16 (one-time) ----------------
__global__ void k_encbf(const float* __restrict__ src, u16* __restrict__ dst, int n8) {
    int i = blockIdx.x * 256 + threadIdx.x;
    if (i < n8) {
        const f32x4 v0 = ((const f32x4*)src)[i*2];
        const f32x4 v1 = ((const f32x4*)src)[i*2 + 1];
        us8 w;
        w[0]=f2bf(v0[0]); w[1]=f2bf(v0[1]); w[2]=f2bf(v0[2]); w[3]=f2bf(v0[3]);
        w[4]=f2bf(v1[0]); w[5]=f2bf(v1[1]); w[6]=f2bf(v1[2]); w[7]=f2bf(v1[3]);
        ((us8*)dst)[i] = w;
    }
}

// ---------------- weight pre-pack into MFMA B-fragment order (unchanged) ----------------
// Layer layout (u16): cq 2x16384 @0 | sa 4x16384 @32768 | ck 6x16384 @98304
//                     | ca 8x16384 @196608 | ff1 @327680 | ff2 @393216 ; stride 458752
__global__ void k_wpack(const float* __restrict__ cq, const float* __restrict__ sa,
                        const float* __restrict__ ck, const float* __restrict__ ca,
                        const float* __restrict__ f1, const float* __restrict__ f2,
                        u16* __restrict__ wp) {
    int f  = blockIdx.x * 256 + threadIdx.x;    // frag id, total 229376
    int l  = f / 57344, fl = f % 57344;
    const float* src; int sk, so, KS, q;
    if (fl < 4096)        { int tap = fl >> 11; q = fl & 2047; KS = 4;
                            src = cq + (size_t)l*49152 + tap;            sk = 3;   so = 384; }
    else if (fl < 12288)  { int j = (fl - 4096) >> 11; q = fl & 2047; KS = 4;
                            src = sa + (size_t)(l*4 + j)*16384;          sk = 128; so = 1;   }
    else if (fl < 24576)  { int ct = (fl - 12288) >> 11; q = fl & 2047; KS = 4;
                            int ci = ct / 3, tap = ct % 3;
                            src = ck + (size_t)(l*2 + ci)*49152 + tap;   sk = 3;   so = 384; }
    else if (fl < 40960)  { int cj = (fl - 24576) >> 11; q = fl & 2047; KS = 4;
                            src = ca + (size_t)(l*8 + cj)*16384;         sk = 128; so = 1;   }
    else if (fl < 49152)  { q = fl - 40960; KS = 4;
                            src = f1 + (size_t)l*65536;                  sk = 512; so = 1;   }
    else                  { q = fl - 49152; KS = 16;
                            src = f2 + (size_t)l*65536;                  sk = 128; so = 1;   }
    int lane = q & 63, tt = q >> 6;
    int ks = tt % KS, ntile = tt / KS;
    int k0 = ks*32 + ((lane >> 4) << 3);
    int o  = ntile*16 + (lane & 15);
    us8 w;
    #pragma unroll
    for (int i = 0; i < 8; i++) w[i] = f2bf(src[(size_t)(k0 + i)*sk + (size_t)o*so]);
    *(us8*)(wp + (size_t)f*8) = w;
}

// ---------------- device helpers (tile = 48 rows x 256 B, XOR swizzle) ----------------
__device__ __forceinline__ void stage48_bf(const u16* __restrict__ src, u16* dst, int t) {
    #pragma unroll
    for (int it = 0; it < 3; it++) {
        int i = t + it*THREADS;                  // 768 us8 chunks (48 rows x 16)
        us8 v = ((const us8*)src)[i];
        int row = i >> 4;
        int colb = (i & 15) << 4;
        *(us8*)((char*)dst + (((row << 8) + colb) ^ ((row & 7) << 4))) = v;
    }
}

__device__ __forceinline__ void stage48_embed(const float* __restrict__ x,
    const float* __restrict__ ew, const float* __restrict__ eb,
    const float* __restrict__ pe, int bn0, u16* dst, int t) {
    #pragma unroll
    for (int it = 0; it < 6; it++) {
        int i = t + it*THREADS;                  // 1536 f32x4 loads
        int elem = i << 2;
        int row = elem >> 7;                     // 0..47
        int col = elem & 127;
        int g = row / 12, s = row - g*12;
        int bn = bn0 + g, b = bn / N_, n = bn - b*N_;
        float xv = x[(b*S_ + s)*N_ + n];
        const f32x4 w  = *(const f32x4*)(ew + col);
        const f32x4 bb = *(const f32x4*)(eb + col);
        const f32x4 p  = *(const f32x4*)(pe + s*E_ + col);
        us4 o; o[0] = f2bf(xv*w[0] + bb[0] + p[0]); o[1] = f2bf(xv*w[1] + bb[1] + p[1]);
               o[2] = f2bf(xv*w[2] + bb[2] + p[2]); o[3] = f2bf(xv*w[3] + bb[3] + p[3]);
        *(us4*)((char*)dst + (((row << 8) + (col << 1)) ^ ((row & 7) << 4))) = o;
    }
}

__device__ __forceinline__ void acc_init(f32x4 (&acc)[3][2], const float* bias, int wave, int lane) {
    #pragma unroll
    for (int nt = 0; nt < 2; nt++) {
        float bv = bias ? bias[(wave*2 + nt)*16 + (lane & 15)] : 0.f;
        #pragma unroll
        for (int mt = 0; mt < 3; mt++) {
            acc[mt][nt][0] = bv; acc[mt][nt][1] = bv; acc[mt][nt][2] = bv; acc[mt][nt][3] = bv;
        }
    }
}

__device__ __forceinline__ bf16x8 ldA(const u16* A, int row, int colb) {
    FragU fu; fu.u = *(const us8*)((const char*)A + (((row << 8) + colb) ^ ((row & 7) << 4)));
    return fu.b;
}

// GEMM: D[48][wave's 32 cols] += A[48][128] * W
template<int KSTOT>
__device__ __forceinline__ void gemm48(const u16* A, const us8* __restrict__ WP, int ksOff,
                                       f32x4 (&acc)[3][2], int wave, int lane) {
    #pragma unroll
    for (int ks = 0; ks < 4; ks++) {
        int colb = (ks*32 + ((lane >> 4) << 3)) << 1;
        bf16x8 a[3];
        #pragma unroll
        for (int mt = 0; mt < 3; mt++) a[mt] = ldA(A, mt*16 + (lane & 15), colb);
        #pragma unroll
        for (int nt = 0; nt < 2; nt++) {
            FragU fb; fb.u = WP[((wave*2 + nt)*KSTOT + ksOff + ks)*64 + lane];
            #pragma unroll
            for (int mt = 0; mt < 3; mt++)
                acc[mt][nt] = __builtin_amdgcn_mfma_f32_16x16x32_bf16(a[mt], fb.b, acc[mt][nt], 0, 0, 0);
        }
    }
}

// GEMM with per-mtile shifted source rows (conv taps; sr<0 -> ZR zero row)
__device__ __forceinline__ void gemm48_rows(const u16* A, const u16* ZR, const int (&sr)[3],
                                            const us8* __restrict__ WP,
                                            f32x4 (&acc)[3][2], int wave, int lane) {
    #pragma unroll
    for (int ks = 0; ks < 4; ks++) {
        int colb = (ks*32 + ((lane >> 4) << 3)) << 1;
        bf16x8 a[3];
        #pragma unroll
        for (int mt = 0; mt < 3; mt++) {
            const char* p = (sr[mt] >= 0)
                ? (const char*)A + (((sr[mt] << 8) + colb) ^ ((sr[mt] & 7) << 4))
                : (const char*)ZR + colb;
            FragU fu; fu.u = *(const us8*)p;
            a[mt] = fu.b;
        }
        #pragma unroll
        for (int nt = 0; nt < 2; nt++) {
            FragU fb; fb.u = WP[((wave*2 + nt)*4 + ks)*64 + lane];
            #pragma unroll
            for (int mt = 0; mt < 3; mt++)
                acc[mt][nt] = __builtin_amdgcn_mfma_f32_16x16x32_bf16(a[mt], fb.b, acc[mt][nt], 0, 0, 0);
        }
    }
}

// Fused 3-output GEMM (QKV): one A-stream, 3 independent acc chains
__device__ __forceinline__ void gemm48_x3(const u16* A,
        const us8* __restrict__ B0, const us8* __restrict__ B1, const us8* __restrict__ B2,
        f32x4 (&c0)[3][2], f32x4 (&c1)[3][2], f32x4 (&c2)[3][2], int wave, int lane) {
    #pragma unroll
    for (int ks = 0; ks < 4; ks++) {
        int colb = (ks*32 + ((lane >> 4) << 3)) << 1;
        bf16x8 a[3];
        #pragma unroll
        for (int mt = 0; mt < 3; mt++) a[mt] = ldA(A, mt*16 + (lane & 15), colb);
        #pragma unroll
        for (int nt = 0; nt < 2; nt++) {
            int bi = ((wave*2 + nt)*4 + ks)*64 + lane;
            FragU f0, f1, f2; f0.u = B0[bi]; f1.u = B1[bi]; f2.u = B2[bi];
            #pragma unroll
            for (int mt = 0; mt < 3; mt++) {
                c0[mt][nt] = __builtin_amdgcn_mfma_f32_16x16x32_bf16(a[mt], f0.b, c0[mt][nt], 0, 0, 0);
                c1[mt][nt] = __builtin_amdgcn_mfma_f32_16x16x32_bf16(a[mt], f1.b, c1[mt][nt], 0, 0, 0);
                c2[mt][nt] = __builtin_amdgcn_mfma_f32_16x16x32_bf16(a[mt], f2.b, c2[mt][nt], 0, 0, 0);
            }
        }
    }
}

// Fused 2-output GEMM (cross K,V)
__device__ __forceinline__ void gemm48_x2(const u16* A,
        const us8* __restrict__ B0, const us8* __restrict__ B1,
        f32x4 (&c0)[3][2], f32x4 (&c1)[3][2], int wave, int lane) {
    #pragma unroll
    for (int ks = 0; ks < 4; ks++) {
        int colb = (ks*32 + ((lane >> 4) << 3)) << 1;
        bf16x8 a[3];
        #pragma unroll
        for (int mt = 0; mt < 3; mt++) a[mt] = ldA(A, mt*16 + (lane & 15), colb);
        #pragma unroll
        for (int nt = 0; nt < 2; nt++) {
            int bi = ((wave*2 + nt)*4 + ks)*64 + lane;
            FragU f0, f1; f0.u = B0[bi]; f1.u = B1[bi];
            #pragma unroll
            for (int mt = 0; mt < 3; mt++) {
                c0[mt][nt] = __builtin_amdgcn_mfma_f32_16x16x32_bf16(a[mt], f0.b, c0[mt][nt], 0, 0, 0);
                c1[mt][nt] = __builtin_amdgcn_mfma_f32_16x16x32_bf16(a[mt], f1.b, c1[mt][nt], 0, 0, 0);
            }
        }
    }
}

template<bool RELU>
__device__ __forceinline__ void acc_store_bf(const f32x4 (&acc)[3][2], u16* Bp, int wave, int lane) {
    #pragma unroll
    for (int mt = 0; mt < 3; mt++)
    #pragma unroll
    for (int nt = 0; nt < 2; nt++)
    #pragma unroll
    for (int r = 0; r < 4; r++) {
        int row = mt*16 + ((lane >> 4) << 2) + r;
        int col = (wave*2 + nt)*16 + (lane & 15);
        float v = acc[mt][nt][r];
        if (RELU) v = fmaxf(v, 0.f);
        *(u16*)((char*)Bp + (((row << 8) + (col << 1)) ^ ((row & 7) << 4))) = f2bf(v);
    }
}

__device__ __forceinline__ void ld16(const u16* Bf, int row, int colb, float* o16) {
    int x = (row & 7) << 4;
    int base = (row << 8) + colb;
    us8 u0 = *(const us8*)((const char*)Bf + (base ^ x));
    us8 u1 = *(const us8*)((const char*)Bf + ((base + 16) ^ x));
    #pragma unroll
    for (int d = 0; d < 8; d++) { o16[d] = bf2f(u0[d]); o16[8+d] = bf2f(u1[d]); }
}

// 384 tasks = 4bn x 8heads x 12 qrows; Q tile replaced in place by attention output
template<bool MASK>
__device__ __forceinline__ void attn48(u16* QA, const u16* KB, const u16* VB, int t) {
    #pragma unroll
    for (int it = 0; it < 2; it++) {
        int task = t + it*THREADS;
        if (task < 384) {
            int g = task / 96, rem = task % 96;
            int hh = rem / 12, qi = rem % 12;
            int hb2 = hh << 5;
            int rq = g*12 + qi;
            float qv[16]; ld16(QA, rq, hb2, qv);
            float sc[12]; float mx = -1e30f;
            #pragma unroll
            for (int j = 0; j < 12; j++) {
                float kv[16]; ld16(KB, g*12 + j, hb2, kv);
                float s = 0.f;
                #pragma unroll
                for (int d = 0; d < 16; d++) s += qv[d]*kv[d];
                s *= 0.25f;
                if (MASK && j > qi) s = -1e30f;
                sc[j] = s; mx = fmaxf(mx, s);
            }
            float sum = 0.f;
            #pragma unroll
            for (int j = 0; j < 12; j++) { sc[j] = __expf(sc[j] - mx); sum += sc[j]; }
            float inv = 1.f/sum;
            float ov[16];
            #pragma unroll
            for (int d = 0; d < 16; d++) ov[d] = 0.f;
            #pragma unroll
            for (int j = 0; j < 12; j++) {
                float vv[16]; ld16(VB, g*12 + j, hb2, vv);
                #pragma unroll
                for (int d = 0; d < 16; d++) ov[d] += sc[j]*vv[d];
            }
            int x = (rq & 7) << 4;
            us8 w0, w1;
            #pragma unroll
            for (int d = 0; d < 8; d++) { w0[d] = f2bf(ov[d]*inv); w1[d] = f2bf(ov[8+d]*inv); }
            *(us8*)((char*)QA + (((rq << 8) + hb2) ^ x))      = w0;
            *(us8*)((char*)QA + (((rq << 8) + hb2 + 16) ^ x)) = w1;
        }
    }
}

// in-register LN; lnbuf = float[384] (aliased into a dead tile); contains one barrier
__device__ __forceinline__ void ln_inreg(f32x4 (&v)[3][2], float* lnbuf,
                                         const float* __restrict__ g, const float* __restrict__ bb,
                                         int wave, int lane) {
    float gc[2], bc[2];
    #pragma unroll
    for (int nt = 0; nt < 2; nt++) {
        int col = (wave*2 + nt)*16 + (lane & 15);
        gc[nt] = g[col]; bc[nt] = bb[col];
    }
    #pragma unroll
    for (int mt = 0; mt < 3; mt++)
    #pragma unroll
    for (int r = 0; r < 4; r++) {
        float a = v[mt][0][r], c = v[mt][1][r];
        float p = a + c, q = a*a + c*c;
        #pragma unroll
        for (int off = 1; off < 16; off <<= 1) { p += __shfl_xor(p, off); q += __shfl_xor(q, off); }
        if ((lane & 15) == 0) {
            int row = mt*16 + ((lane >> 4) << 2) + r;
            lnbuf[(row*4 + wave)*2]     = p;
            lnbuf[(row*4 + wave)*2 + 1] = q;
        }
    }
    __syncthreads();
    #pragma unroll
    for (int mt = 0; mt < 3; mt++)
    #pragma unroll
    for (int r = 0; r < 4; r++) {
        int row = mt*16 + ((lane >> 4) << 2) + r;
        float sum = 0.f, ss = 0.f;
        #pragma unroll
        for (int w2 = 0; w2 < 4; w2++) { sum += lnbuf[(row*4 + w2)*2]; ss += lnbuf[(row*4 + w2)*2 + 1]; }
        float m   = sum * (1.f/128.f);
        float var = ss * (1.f/128.f) - m*m;
        float inv = rsqrtf(var + EPS_);
        #pragma unroll
        for (int nt = 0; nt < 2; nt++)
            v[mt][nt][r] = (v[mt][nt][r] - m)*inv*gc[nt] + bc[nt];
    }
}

// ---------------- whole decoder layer, fused (4 bn per block, 4 waves) ----------------
template<bool EMB, bool FIN>
__global__ void __launch_bounds__(THREADS, 2)
k_layer(u16* __restrict__ hb, const float* __restrict__ x,
        const float* __restrict__ ew, const float* __restrict__ ebp, const float* __restrict__ pe,
        const u16* __restrict__ encb, const u16* __restrict__ lw,
        const float* __restrict__ sab, const float* __restrict__ ckb, const float* __restrict__ cab,
        const float* __restrict__ fb1, const float* __restrict__ fb2,
        const float* __restrict__ lg, const float* __restrict__ lb,
        const float* __restrict__ fcw, const float* __restrict__ fcb,
        float* __restrict__ outp) {
    __shared__ __align__(16) u16 P0[6144], P1[6144], P2[6144], P3[6144], P4[6144], ZR[128];
    float* lnbuf = (float*)P2;   // P2 dead at every LN call site (barrier-separated)

    int t = threadIdx.x, wave = t >> 6, lane = t & 63;
    int bid = blockIdx.x;
    u16* hp = hb + (size_t)(bid*4) * (S_*E_);

    if (t < 64) ((unsigned*)ZR)[t] = 0;
    // I1: stage h -> P0, prefetch enc0 -> P4
    if (EMB) stage48_embed(x, ew, ebp, pe, bid*4, P0, t);
    else     stage48_bf(hp, P0, t);
    stage48_bf(encb + (size_t)(bid*4) * (S_*E_), P4, t);
    __syncthreads();                                               // B1

    int gg[3], rr[3];
    #pragma unroll
    for (int mt = 0; mt < 3; mt++) { int m = mt*16 + (lane & 15); gg[mt] = m/12; rr[mt] = m - gg[mt]*12; }
    int srp[3], srf[3], srn[3];
    #pragma unroll
    for (int mt = 0; mt < 3; mt++) {
        srp[mt] = (rr[mt] >= 1)     ? gg[mt]*12 + rr[mt] - 1 : -1;
        srf[mt] = gg[mt]*12 + rr[mt];
        srn[mt] = (rr[mt] + 1 < 12) ? gg[mt]*12 + rr[mt] + 1 : -1;
    }

    // I2: SELF causal conv (residual kept in regs)
    f32x4 cacc[3][2];
    acc_init(cacc, nullptr, wave, lane);
    gemm48_rows(P0, ZR, srp, (const us8*)lw,           cacc, wave, lane);
    gemm48_rows(P0, ZR, srf, (const us8*)(lw + 16384), cacc, wave, lane);
    acc_store_bf<false>(cacc, P1, wave, lane);                     // conv out
    __syncthreads();                                               // B2

    // I3: fused QKV (A = P1) -> Q:P0, K:P2, V:P3
    {
        const us8* sap = (const us8*)(lw + 32768);
        f32x4 aq[3][2], ak[3][2], av[3][2];
        acc_init(aq, sab,       wave, lane);
        acc_init(ak, sab + 128, wave, lane);
        acc_init(av, sab + 256, wave, lane);
        gemm48_x3(P1, sap, sap + 2048, sap + 4096, aq, ak, av, wave, lane);
        acc_store_bf<false>(aq, P0, wave, lane);
        acc_store_bf<false>(ak, P2, wave, lane);
        acc_store_bf<false>(av, P3, wave, lane);
    }
    __syncthreads();                                               // B3
    attn48<true>(P0, P2, P3, t);                                   // I4
    __syncthreads();                                               // B4

    // I5: out-proj + residual + LN1 -> h1 in P1 ; encconv0 (P4 -> ES0 in P3)
    f32x4 hres[3][2];
    {
        f32x4 a[3][2];
        acc_init(a, sab + 384, wave, lane);
        gemm48<4>(P0, (const us8*)(lw + 81920), 0, a, wave, lane);
        #pragma unroll
        for (int mt = 0; mt < 3; mt++)
        #pragma unroll
        for (int nt = 0; nt < 2; nt++) hres[mt][nt] = a[mt][nt] + cacc[mt][nt];
    }
    ln_inreg(hres, lnbuf, lg, lb, wave, lane);                     // internal barrier
    acc_store_bf<false>(hres, P1, wave, lane);                     // h1
    {
        const us8* ckp = (const us8*)(lw + 98304);
        f32x4 a[3][2];
        acc_init(a, ckb, wave, lane);
        gemm48_rows(P4, ZR, srp, ckp,        a, wave, lane);
        gemm48_rows(P4, ZR, srf, ckp + 2048, a, wave, lane);
        gemm48_rows(P4, ZR, srn, ckp + 4096, a, wave, lane);
        acc_store_bf<false>(a, P3, wave, lane);                    // ES0
    }
    __syncthreads();                                               // B5

    // ---- CROSS (2 encoders, averaged) ----
    f32x4 creg[3][2];
    #pragma unroll
    for (int nt = 0; nt < 2; nt++) {
        int col = (wave*2 + nt)*16 + (lane & 15);
        float bv = cab[3*128 + col] + cab[7*128 + col];
        #pragma unroll
        for (int mt = 0; mt < 3; mt++) { creg[mt][nt][0]=bv; creg[mt][nt][1]=bv; creg[mt][nt][2]=bv; creg[mt][nt][3]=bv; }
    }

    const us8* cap0 = (const us8*)(lw + 196608);
    {   // I6: QKV0 -- Q0<-P1 -> P0 ; K0,V0 <- ES0(P3) -> P2,P4 (enc0 consumed)
        f32x4 aq[3][2], ak[3][2], av[3][2];
        acc_init(aq, cab, wave, lane);
        gemm48<4>(P1, cap0, 0, aq, wave, lane);
        acc_store_bf<false>(aq, P0, wave, lane);
        acc_init(ak, cab + 128, wave, lane);
        acc_init(av, cab + 256, wave, lane);
        gemm48_x2(P3, cap0 + 2048, cap0 + 4096, ak, av, wave, lane);
        acc_store_bf<false>(ak, P2, wave, lane);                   // K0
        acc_store_bf<false>(av, P4, wave, lane);                   // V0
    }
    __syncthreads();                                               // B6
    stage48_bf(encb + ((size_t)BN_ + bid*4) * (S_*E_), P3, t);     // enc1 -> P3 (ES0 dead)
    attn48<false>(P0, P2, P4, t);                                  // I7
    __syncthreads();                                               // B7

    // I8 (merged): out-proj 0 (reads P0=AO0) + encconv1 (reads P3=enc1, writes P4=dead V0)
    gemm48<4>(P0, cap0 + 6144, 0, creg, wave, lane);
    {
        const us8* ckp = (const us8*)(lw + 98304 + 3*16384);
        f32x4 a[3][2];
        acc_init(a, ckb + 128, wave, lane);
        gemm48_rows(P3, ZR, srp, ckp,        a, wave, lane);
        gemm48_rows(P3, ZR, srf, ckp + 2048, a, wave, lane);
        gemm48_rows(P3, ZR, srn, ckp + 4096, a, wave, lane);
        acc_store_bf<false>(a, P4, wave, lane);                    // ES1
    }
    __syncthreads();                                               // B8

    const us8* cap1 = (const us8*)(lw + 196608 + 4*16384);
    {   // I9: QKV1 -- Q1<-P1 -> P0 (AO0 dead) ; K1,V1 <- ES1(P4) -> P2 (K0 dead), P3 (enc1 consumed)
        f32x4 aq[3][2], ak[3][2], av[3][2];
        acc_init(aq, cab + 4*128, wave, lane);
        gemm48<4>(P1, cap1, 0, aq, wave, lane);
        acc_store_bf<false>(aq, P0, wave, lane);
        acc_init(ak, cab + 5*128, wave, lane);
        acc_init(av, cab + 6*128, wave, lane);
        gemm48_x2(P4, cap1 + 2048, cap1 + 4096, ak, av, wave, lane);
        acc_store_bf<false>(ak, P2, wave, lane);                   // K1
        acc_store_bf<false>(av, P3, wave, lane);                   // V1
    }
    __syncthreads();                                               // B9
    attn48<false>(P0, P2, P3, t);                                  // I10
    __syncthreads();                                               // B10

    // I11: out-proj 1 + cross residual + LN2 + h2 store (lnbuf=P2: K1 dead since B10)
    gemm48<4>(P0, cap1 + 6144, 0, creg, wave, lane);
    #pragma unroll
    for (int mt = 0; mt < 3; mt++)
    #pragma unroll
    for (int nt = 0; nt < 2; nt++) hres[mt][nt] = hres[mt][nt] + 0.5f*creg[mt][nt];
    ln_inreg(hres, lnbuf, lg + 128, lb + 128, wave, lane);         // internal barrier
    acc_store_bf<false>(hres, P1, wave, lane);                     // h2 (FFN input)
    __syncthreads();                                               // B11

    // ---- FFN: 2 halves of 256 cols (mid half -> P2+P3, then ff2 over both) ----
    f32x4 ffacc[3][2];
    acc_init(ffacc, fb2, wave, lane);
    #pragma unroll
    for (int half = 0; half < 2; half++) {
        {
            f32x4 a[3][2];
            acc_init(a, fb1 + (half*2)*128, wave, lane);
            gemm48<4>(P1, (const us8*)(lw + 327680) + (half*2)*2048, 0, a, wave, lane);
            acc_store_bf<true>(a, P2, wave, lane);
        }
        {
            f32x4 a[3][2];
            acc_init(a, fb1 + (half*2 + 1)*128, wave, lane);
            gemm48<4>(P1, (const us8*)(lw + 327680) + (half*2 + 1)*2048, 0, a, wave, lane);
            acc_store_bf<true>(a, P3, wave, lane);
        }
        __syncthreads();                                           // B12 / B14
        gemm48<16>(P2, (const us8*)(lw + 393216), (half*2)*4,     ffacc, wave, lane);
        gemm48<16>(P3, (const us8*)(lw + 393216), (half*2 + 1)*4, ffacc, wave, lane);
        __syncthreads();                                           // B13 / B15
    }
    #pragma unroll
    for (int mt = 0; mt < 3; mt++)
    #pragma unroll
    for (int nt = 0; nt < 2; nt++) hres[mt][nt] = hres[mt][nt] + ffacc[mt][nt];
    // B15 guarantees all P2 reads complete -> lnbuf (aliasing P2) safe
    ln_inreg(hres, lnbuf, lg + 256, lb + 256, wave, lane);         // internal barrier

    if (FIN) {
        // fused final projection (OUT=1) with output transpose
        float fw[2];
        #pragma unroll
        for (int nt = 0; nt < 2; nt++) fw[nt] = fcw[(wave*2 + nt)*16 + (lane & 15)];
        float pr[3][4];
        #pragma unroll
        for (int mt = 0; mt < 3; mt++)
        #pragma unroll
        for (int r = 0; r < 4; r++) {
            float p = hres[mt][0][r]*fw[0] + hres[mt][1][r]*fw[1];
            #pragma unroll
            for (int off = 1; off < 16; off <<= 1) p += __shfl_xor(p, off);
            pr[mt][r] = p;
        }
        __syncthreads();                                           // lnbuf readers done
        if ((lane & 15) == 0) {
            #pragma unroll
            for (int mt = 0; mt < 3; mt++)
            #pragma unroll
            for (int r = 0; r < 4; r++) {
                int row = mt*16 + ((lane >> 4) << 2) + r;
                lnbuf[row*4 + wave] = pr[mt][r];
            }
        }
        __syncthreads();
        if (t < 48) {
            float s4 = lnbuf[t*4] + lnbuf[t*4+1] + lnbuf[t*4+2] + lnbuf[t*4+3] + fcb[0];
            int bn = bid*4 + t/12, s = t % 12;
            int b = bn / N_, n = bn - b*N_;
            outp[(b*S_ + s)*N_ + n] = s4;
        }
    } else {
        #pragma unroll
        for (int mt = 0; mt < 3; mt++)
        #pragma unroll
        for (int nt = 0; nt < 2; nt++)
        #pragma unroll
        for (int r = 0; r < 4; r++) {
            int row = mt*16 + ((lane >> 4) << 2) + r;
            int col = (wave*2 + nt)*16 + (lane & 15);
            hp[row*E_ + col] = f2bf(hres[mt][nt][r]);
        }
    }
}

extern "C" void kernel_launch(void* const* d_in, const int* in_sizes, int n_in,
                              void* d_out, int out_size, void* d_ws, size_t ws_size,
                              hipStream_t stream) {
    const float* x        = (const float*)d_in[0];
    const float* enc_x    = (const float*)d_in[1];
    const float* emb_w    = (const float*)d_in[3];
    const float* emb_b    = (const float*)d_in[4];
    const float* pe       = (const float*)d_in[5];
    const float* conv_q_w = (const float*)d_in[6];
    const float* conv_k_w = (const float*)d_in[7];
    const float* conv_k_b = (const float*)d_in[8];
    const float* sa_w     = (const float*)d_in[9];
    const float* sa_b     = (const float*)d_in[10];
    const float* ca_w     = (const float*)d_in[11];
    const float* ca_b     = (const float*)d_in[12];
    const float* ff_w1    = (const float*)d_in[13];
    const float* ff_b1    = (const float*)d_in[14];
    const float* ff_w2    = (const float*)d_in[15];
    const float* ff_b2    = (const float*)d_in[16];
    const float* ln_g     = (const float*)d_in[17];
    const float* ln_b     = (const float*)d_in[18];
    const float* fc_w     = (const float*)d_in[19];
    const float* fc_b     = (const float*)d_in[20];

    const size_t HN = (size_t)BN_ * S_ * E_;    // 16,711,680 elems
    u16* hb   = (u16*)d_ws;                     // h bf16
    u16* encb = hb + HN;                        // enc bf16 (2*HN)
    u16* wpk  = encb + 2*HN;

    {
        int n8 = (int)(2*HN/8);                 // 4,177,920
        k_encbf<<<(n8 + 255)/256, 256, 0, stream>>>(enc_x, encb, n8);
    }
    k_wpack<<<896, 256, 0, stream>>>(conv_q_w, sa_w, conv_k_w, ca_w, ff_w1, ff_w2, wpk);

    for (int l = 0; l < L_; l++) {
        const u16* lw = wpk + (size_t)l*458752;
        const float* sab = sa_b + l*512;
        const float* ckb = conv_k_b + l*256;
        const float* cab = ca_b + l*1024;
        const float* fb1 = ff_b1 + l*512;
        const float* fb2 = ff_b2 + l*128;
        const float* lg  = ln_g + l*384;
        const float* lb  = ln_b + l*384;
        if (l == 0)
            k_layer<true, false><<<BN_/4, THREADS, 0, stream>>>(hb, x, emb_w, emb_b, pe, encb, lw,
                sab, ckb, cab, fb1, fb2, lg, lb, fc_w, fc_b, (float*)d_out);
        else if (l == L_-1)
            k_layer<false, true><<<BN_/4, THREADS, 0, stream>>>(hb, x, emb_w, emb_b, pe, encb, lw,
                sab, ckb, cab, fb1, fb2, lg, lb, fc_w, fc_b, (float*)d_out);
        else
            k_layer<false, false><<<BN_/4, THREADS, 0, stream>>>(hb, x, emb_w, emb_b, pe, encb, lw,
                sab, ckb, cab, fb1, fb2, lg, lb, fc_w, fc_b, (float*)d_out);
    }
}

// Round 22
// 1521.261 us; speedup vs baseline: 1.0559x; 1.0559x over previous
//
#include <hip/hip_runtime.h>

// f32 accumulate; bf16 MFMA inputs. One fused kernel per layer (weights L2-hot).
// FINAL (R20 revert, measured best 1521 us): 2 bn/block, 256 thr / 4 waves, NTW=2,
// 32-row tiles (pad rows zeroed at stage); interval-merged schedule (~16 barriers);
// FFN as 2x256-col halves; h/enc bf16 in ws; lnbuf aliased into P2.
// LDS = 5*8192 = 40960 B. __launch_bounds__(256,2) => VGPR cap 128 (no spill at 120).
// R21 falsified the weight-BW hypothesis (half traffic, same 428 us/layer) and
// re-spilled (3-M-tile x3 fusion > 128 VGPR) => this structure is the optimum found.

#define B_   64
#define S_   12
#define N_   170
#define BN_  (B_*N_)      // 10880
#define E_   128
#define L_   4
#define C_   2
#define H_   8
#define DH_  16
#define FF_  512
#define EPS_ 1e-5f
#define THREADS 256

typedef unsigned short u16;
typedef __attribute__((ext_vector_type(4))) float f32x4;
typedef __attribute__((ext_vector_type(8))) u16   us8;
typedef __attribute__((ext_vector_type(4))) u16   us4;
typedef __attribute__((ext_vector_type(8))) __bf16 bf16x8;
union FragU { us8 u; bf16x8 b; };

__device__ __forceinline__ u16 f2bf(float f) {
    __bf16 h = (__bf16)f;
    return __builtin_bit_cast(u16, h);
}
__device__ __forceinline__ float bf2f(u16 s) {
    return __builtin_bit_cast(float, (unsigned)s << 16);
}

// ---------------- enc_x f32 -> bf16 (one-time) ----------------
__global__ void k_encbf(const float* __restrict__ src, u16* __restrict__ dst, int n8) {
    int i = blockIdx.x * 256 + threadIdx.x;
    if (i < n8) {
        const f32x4 v0 = ((const f32x4*)src)[i*2];
        const f32x4 v1 = ((const f32x4*)src)[i*2 + 1];
        us8 w;
        w[0]=f2bf(v0[0]); w[1]=f2bf(v0[1]); w[2]=f2bf(v0[2]); w[3]=f2bf(v0[3]);
        w[4]=f2bf(v1[0]); w[5]=f2bf(v1[1]); w[6]=f2bf(v1[2]); w[7]=f2bf(v1[3]);
        ((us8*)dst)[i] = w;
    }
}

// ---------------- weight pre-pack into MFMA B-fragment order ----------------
// Layer layout (u16): cq 2x16384 @0 | sa 4x16384 @32768 | ck 6x16384 @98304
//                     | ca 8x16384 @196608 | ff1 @327680 | ff2 @393216 ; stride 458752
__global__ void k_wpack(const float* __restrict__ cq, const float* __restrict__ sa,
                        const float* __restrict__ ck, const float* __restrict__ ca,
                        const float* __restrict__ f1, const float* __restrict__ f2,
                        u16* __restrict__ wp) {
    int f  = blockIdx.x * 256 + threadIdx.x;    // frag id, total 229376
    int l  = f / 57344, fl = f % 57344;
    const float* src; int sk, so, KS, q;
    if (fl < 4096)        { int tap = fl >> 11; q = fl & 2047; KS = 4;
                            src = cq + (size_t)l*49152 + tap;            sk = 3;   so = 384; }
    else if (fl < 12288)  { int j = (fl - 4096) >> 11; q = fl & 2047; KS = 4;
                            src = sa + (size_t)(l*4 + j)*16384;          sk = 128; so = 1;   }
    else if (fl < 24576)  { int ct = (fl - 12288) >> 11; q = fl & 2047; KS = 4;
                            int ci = ct / 3, tap = ct % 3;
                            src = ck + (size_t)(l*2 + ci)*49152 + tap;   sk = 3;   so = 384; }
    else if (fl < 40960)  { int cj = (fl - 24576) >> 11; q = fl & 2047; KS = 4;
                            src = ca + (size_t)(l*8 + cj)*16384;         sk = 128; so = 1;   }
    else if (fl < 49152)  { q = fl - 40960; KS = 4;
                            src = f1 + (size_t)l*65536;                  sk = 512; so = 1;   }
    else                  { q = fl - 49152; KS = 16;
                            src = f2 + (size_t)l*65536;                  sk = 128; so = 1;   }
    int lane = q & 63, tt = q >> 6;
    int ks = tt % KS, ntile = tt / KS;
    int k0 = ks*32 + ((lane >> 4) << 3);
    int o  = ntile*16 + (lane & 15);
    us8 w;
    #pragma unroll
    for (int i = 0; i < 8; i++) w[i] = f2bf(src[(size_t)(k0 + i)*sk + (size_t)o*so]);
    *(us8*)(wp + (size_t)f*8) = w;
}

// ---------------- device helpers (tile = 32 rows x 256 B, XOR swizzle) ----------------
// Tile holds 2 bn: rows g*16 + s (s<12 real; 12-15 / 28-31 garbage, zeroed at stage).
__device__ __forceinline__ void zero_pad_rows(u16* dst, int t) {
    if (t < 128) {                               // 8 rows x 16 us8 chunks
        int chunk = t & 15, ridx = t >> 4;
        int row = 12 + (ridx & 3) + ((ridx >> 2) << 4);   // 12-15, 28-31
        us8 z = {0,0,0,0,0,0,0,0};
        *(us8*)((char*)dst + (((row << 8) + (chunk << 4)) ^ ((row & 7) << 4))) = z;
    }
}

__device__ __forceinline__ void stage24_bf(const u16* __restrict__ src, u16* dst, int t) {
    for (int i = t; i < 384; i += THREADS) {     // 384 us8 loads (24 rows x 128)
        us8 v = ((const us8*)src)[i];
        int row = i >> 4;                        // 0..23
        int g = row / 12, s = row - g*12;
        int rowT = g*16 + s;
        int colb = (i & 15) << 4;
        *(us8*)((char*)dst + (((rowT << 8) + colb) ^ ((rowT & 7) << 4))) = v;
    }
    zero_pad_rows(dst, t);
}

__device__ __forceinline__ void stage24_embed(const float* __restrict__ x,
    const float* __restrict__ ew, const float* __restrict__ eb,
    const float* __restrict__ pe, int bn0, u16* dst, int t) {
    #pragma unroll
    for (int it = 0; it < 3; it++) {
        int i = t + it*THREADS;                  // 768 f32x4 loads
        int elem = i << 2;
        int srow = elem >> 7;
        int g = srow / 12, s = srow - g*12;
        int row = g*16 + s;
        int col = elem & 127;
        int bn = bn0 + g, b = bn / N_, n = bn - b*N_;
        float xv = x[(b*S_ + s)*N_ + n];
        const f32x4 w  = *(const f32x4*)(ew + col);
        const f32x4 bb = *(const f32x4*)(eb + col);
        const f32x4 p  = *(const f32x4*)(pe + s*E_ + col);
        us4 o; o[0] = f2bf(xv*w[0] + bb[0] + p[0]); o[1] = f2bf(xv*w[1] + bb[1] + p[1]);
               o[2] = f2bf(xv*w[2] + bb[2] + p[2]); o[3] = f2bf(xv*w[3] + bb[3] + p[3]);
        *(us4*)((char*)dst + (((row << 8) + (col << 1)) ^ ((row & 7) << 4))) = o;
    }
    zero_pad_rows(dst, t);
}

__device__ __forceinline__ void acc_init(f32x4 (&acc)[2][2], const float* bias, int wave, int lane) {
    #pragma unroll
    for (int nt = 0; nt < 2; nt++) {
        float bv = bias ? bias[(wave*2 + nt)*16 + (lane & 15)] : 0.f;
        #pragma unroll
        for (int mt = 0; mt < 2; mt++) {
            acc[mt][nt][0] = bv; acc[mt][nt][1] = bv; acc[mt][nt][2] = bv; acc[mt][nt][3] = bv;
        }
    }
}

__device__ __forceinline__ bf16x8 ldA(const u16* A, int row, int colb) {
    FragU fu; fu.u = *(const us8*)((const char*)A + (((row << 8) + colb) ^ ((row & 7) << 4)));
    return fu.b;
}

// GEMM: D[32][wave's 32 cols] += A[32][128] * W
template<int KSTOT>
__device__ __forceinline__ void gemm24(const u16* A, const us8* __restrict__ WP, int ksOff,
                                       f32x4 (&acc)[2][2], int wave, int lane) {
    #pragma unroll
    for (int ks = 0; ks < 4; ks++) {
        int colb = (ks*32 + ((lane >> 4) << 3)) << 1;
        bf16x8 a[2];
        #pragma unroll
        for (int mt = 0; mt < 2; mt++) a[mt] = ldA(A, mt*16 + (lane & 15), colb);
        #pragma unroll
        for (int nt = 0; nt < 2; nt++) {
            FragU fb; fb.u = WP[((wave*2 + nt)*KSTOT + ksOff + ks)*64 + lane];
            #pragma unroll
            for (int mt = 0; mt < 2; mt++)
                acc[mt][nt] = __builtin_amdgcn_mfma_f32_16x16x32_bf16(a[mt], fb.b, acc[mt][nt], 0, 0, 0);
        }
    }
}

// GEMM with per-mtile shifted source rows (conv taps; redirect rows are zeroed pads)
__device__ __forceinline__ void gemm24_rows(const u16* A, const int (&sr)[2],
                                            const us8* __restrict__ WP,
                                            f32x4 (&acc)[2][2], int wave, int lane) {
    #pragma unroll
    for (int ks = 0; ks < 4; ks++) {
        int colb = (ks*32 + ((lane >> 4) << 3)) << 1;
        bf16x8 a[2];
        #pragma unroll
        for (int mt = 0; mt < 2; mt++) a[mt] = ldA(A, sr[mt], colb);
        #pragma unroll
        for (int nt = 0; nt < 2; nt++) {
            FragU fb; fb.u = WP[((wave*2 + nt)*4 + ks)*64 + lane];
            #pragma unroll
            for (int mt = 0; mt < 2; mt++)
                acc[mt][nt] = __builtin_amdgcn_mfma_f32_16x16x32_bf16(a[mt], fb.b, acc[mt][nt], 0, 0, 0);
        }
    }
}

// Fused 3-output GEMM (QKV): one A-stream, 3 independent acc chains
__device__ __forceinline__ void gemm24_x3(const u16* A,
        const us8* __restrict__ B0, const us8* __restrict__ B1, const us8* __restrict__ B2,
        f32x4 (&c0)[2][2], f32x4 (&c1)[2][2], f32x4 (&c2)[2][2], int wave, int lane) {
    #pragma unroll
    for (int ks = 0; ks < 4; ks++) {
        int colb = (ks*32 + ((lane >> 4) << 3)) << 1;
        bf16x8 a[2];
        #pragma unroll
        for (int mt = 0; mt < 2; mt++) a[mt] = ldA(A, mt*16 + (lane & 15), colb);
        #pragma unroll
        for (int nt = 0; nt < 2; nt++) {
            int bi = ((wave*2 + nt)*4 + ks)*64 + lane;
            FragU f0, f1, f2; f0.u = B0[bi]; f1.u = B1[bi]; f2.u = B2[bi];
            #pragma unroll
            for (int mt = 0; mt < 2; mt++) {
                c0[mt][nt] = __builtin_amdgcn_mfma_f32_16x16x32_bf16(a[mt], f0.b, c0[mt][nt], 0, 0, 0);
                c1[mt][nt] = __builtin_amdgcn_mfma_f32_16x16x32_bf16(a[mt], f1.b, c1[mt][nt], 0, 0, 0);
                c2[mt][nt] = __builtin_amdgcn_mfma_f32_16x16x32_bf16(a[mt], f2.b, c2[mt][nt], 0, 0, 0);
            }
        }
    }
}

// Fused 2-output GEMM (cross K,V)
__device__ __forceinline__ void gemm24_x2(const u16* A,
        const us8* __restrict__ B0, const us8* __restrict__ B1,
        f32x4 (&c0)[2][2], f32x4 (&c1)[2][2], int wave, int lane) {
    #pragma unroll
    for (int ks = 0; ks < 4; ks++) {
        int colb = (ks*32 + ((lane >> 4) << 3)) << 1;
        bf16x8 a[2];
        #pragma unroll
        for (int mt = 0; mt < 2; mt++) a[mt] = ldA(A, mt*16 + (lane & 15), colb);
        #pragma unroll
        for (int nt = 0; nt < 2; nt++) {
            int bi = ((wave*2 + nt)*4 + ks)*64 + lane;
            FragU f0, f1; f0.u = B0[bi]; f1.u = B1[bi];
            #pragma unroll
            for (int mt = 0; mt < 2; mt++) {
                c0[mt][nt] = __builtin_amdgcn_mfma_f32_16x16x32_bf16(a[mt], f0.b, c0[mt][nt], 0, 0, 0);
                c1[mt][nt] = __builtin_amdgcn_mfma_f32_16x16x32_bf16(a[mt], f1.b, c1[mt][nt], 0, 0, 0);
            }
        }
    }
}

template<bool RELU>
__device__ __forceinline__ void acc_store_bf(const f32x4 (&acc)[2][2], u16* Bp, int wave, int lane) {
    #pragma unroll
    for (int mt = 0; mt < 2; mt++)
    #pragma unroll
    for (int nt = 0; nt < 2; nt++)
    #pragma unroll
    for (int r = 0; r < 4; r++) {
        int row = mt*16 + ((lane >> 4) << 2) + r;
        int col = (wave*2 + nt)*16 + (lane & 15);
        float v = acc[mt][nt][r];
        if (RELU) v = fmaxf(v, 0.f);
        *(u16*)((char*)Bp + (((row << 8) + (col << 1)) ^ ((row & 7) << 4))) = f2bf(v);
    }
}

__device__ __forceinline__ void ld16(const u16* Bf, int row, int colb, float* o16) {
    int x = (row & 7) << 4;
    int base = (row << 8) + colb;
    us8 u0 = *(const us8*)((const char*)Bf + (base ^ x));
    us8 u1 = *(const us8*)((const char*)Bf + ((base + 16) ^ x));
    #pragma unroll
    for (int d = 0; d < 8; d++) { o16[d] = bf2f(u0[d]); o16[8+d] = bf2f(u1[d]); }
}

// 192 tasks = 2bn x 8heads x 12 qrows; Q tile replaced in place by attention output
template<bool MASK>
__device__ __forceinline__ void attn24(u16* QA, const u16* KB, const u16* VB, int t) {
    if (t < 192) {
        int g = t / 96, rem = t % 96;
        int hh = rem / 12, qi = rem % 12;
        int hb2 = hh << 5;
        int rq = g*16 + qi;
        float qv[16]; ld16(QA, rq, hb2, qv);
        float sc[12]; float mx = -1e30f;
        #pragma unroll
        for (int j = 0; j < 12; j++) {
            float kv[16]; ld16(KB, g*16 + j, hb2, kv);
            float s = 0.f;
            #pragma unroll
            for (int d = 0; d < 16; d++) s += qv[d]*kv[d];
            s *= 0.25f;
            if (MASK && j > qi) s = -1e30f;
            sc[j] = s; mx = fmaxf(mx, s);
        }
        float sum = 0.f;
        #pragma unroll
        for (int j = 0; j < 12; j++) { sc[j] = __expf(sc[j] - mx); sum += sc[j]; }
        float inv = 1.f/sum;
        float ov[16];
        #pragma unroll
        for (int d = 0; d < 16; d++) ov[d] = 0.f;
        #pragma unroll
        for (int j = 0; j < 12; j++) {
            float vv[16]; ld16(VB, g*16 + j, hb2, vv);
            #pragma unroll
            for (int d = 0; d < 16; d++) ov[d] += sc[j]*vv[d];
        }
        int x = (rq & 7) << 4;
        us8 w0, w1;
        #pragma unroll
        for (int d = 0; d < 8; d++) { w0[d] = f2bf(ov[d]*inv); w1[d] = f2bf(ov[8+d]*inv); }
        *(us8*)((char*)QA + (((rq << 8) + hb2) ^ x))      = w0;
        *(us8*)((char*)QA + (((rq << 8) + hb2 + 16) ^ x)) = w1;
    }
}

// in-register LN; lnbuf = float[256] (aliased into a dead tile); contains one barrier
__device__ __forceinline__ void ln_inreg(f32x4 (&v)[2][2], float* lnbuf,
                                         const float* __restrict__ g, const float* __restrict__ bb,
                                         int wave, int lane) {
    float gc[2], bc[2];
    #pragma unroll
    for (int nt = 0; nt < 2; nt++) {
        int col = (wave*2 + nt)*16 + (lane & 15);
        gc[nt] = g[col]; bc[nt] = bb[col];
    }
    #pragma unroll
    for (int mt = 0; mt < 2; mt++)
    #pragma unroll
    for (int r = 0; r < 4; r++) {
        float a = v[mt][0][r], c = v[mt][1][r];
        float p = a + c, q = a*a + c*c;
        #pragma unroll
        for (int off = 1; off < 16; off <<= 1) { p += __shfl_xor(p, off); q += __shfl_xor(q, off); }
        if ((lane & 15) == 0) {
            int row = mt*16 + ((lane >> 4) << 2) + r;
            lnbuf[(row*4 + wave)*2]     = p;
            lnbuf[(row*4 + wave)*2 + 1] = q;
        }
    }
    __syncthreads();
    #pragma unroll
    for (int mt = 0; mt < 2; mt++)
    #pragma unroll
    for (int r = 0; r < 4; r++) {
        int row = mt*16 + ((lane >> 4) << 2) + r;
        float sum = 0.f, ss = 0.f;
        #pragma unroll
        for (int w2 = 0; w2 < 4; w2++) { sum += lnbuf[(row*4 + w2)*2]; ss += lnbuf[(row*4 + w2)*2 + 1]; }
        float m   = sum * (1.f/128.f);
        float var = ss * (1.f/128.f) - m*m;
        float inv = rsqrtf(var + EPS_);
        #pragma unroll
        for (int nt = 0; nt < 2; nt++)
            v[mt][nt][r] = (v[mt][nt][r] - m)*inv*gc[nt] + bc[nt];
    }
}

// ---------------- whole decoder layer, fused (2 bn per block, 4 waves) ----------------
template<bool EMB, bool FIN>
__global__ void __launch_bounds__(THREADS, 2)
k_layer(u16* __restrict__ hb, const float* __restrict__ x,
        const float* __restrict__ ew, const float* __restrict__ ebp, const float* __restrict__ pe,
        const u16* __restrict__ encb, const u16* __restrict__ lw,
        const float* __restrict__ sab, const float* __restrict__ ckb, const float* __restrict__ cab,
        const float* __restrict__ fb1, const float* __restrict__ fb2,
        const float* __restrict__ lg, const float* __restrict__ lb,
        const float* __restrict__ fcw, const float* __restrict__ fcb,
        float* __restrict__ outp) {
    __shared__ __align__(16) u16 P0[4096], P1[4096], P2[4096], P3[4096], P4[4096];
    float* lnbuf = (float*)P2;   // P2 is dead at every LN call site (barrier-separated)

    int t = threadIdx.x, wave = t >> 6, lane = t & 63;
    int bid = blockIdx.x;
    u16* hp = hb + (size_t)(bid*2) * (S_*E_);

    // I1: stage h -> P0, prefetch enc0 -> P4 (garbage rows zeroed at stage)
    if (EMB) stage24_embed(x, ew, ebp, pe, bid*2, P0, t);
    else     stage24_bf(hp, P0, t);
    stage24_bf(encb + (size_t)(bid*2) * (S_*E_), P4, t);
    __syncthreads();                                               // B1

    int rr = lane & 15;
    int srp[2], srf[2], srn[2];
    #pragma unroll
    for (int mt = 0; mt < 2; mt++) {
        srp[mt] = (rr >= 1)     ? mt*16 + rr - 1 : mt*16 + 12;   // redirect -> zeroed pad
        srf[mt] = mt*16 + rr;
        srn[mt] = (rr + 1 < 12) ? mt*16 + rr + 1 : mt*16 + 12;
    }

    // I2: SELF causal conv (residual kept in regs)
    f32x4 cacc[2][2];
    acc_init(cacc, nullptr, wave, lane);
    gemm24_rows(P0, srp, (const us8*)lw,           cacc, wave, lane);
    gemm24_rows(P0, srf, (const us8*)(lw + 16384), cacc, wave, lane);
    acc_store_bf<false>(cacc, P1, wave, lane);                     // conv out
    __syncthreads();                                               // B2

    // I3: fused QKV (A = P1) -> Q:P0, K:P2, V:P3
    {
        const us8* sap = (const us8*)(lw + 32768);
        f32x4 aq[2][2], ak[2][2], av[2][2];
        acc_init(aq, sab,       wave, lane);
        acc_init(ak, sab + 128, wave, lane);
        acc_init(av, sab + 256, wave, lane);
        gemm24_x3(P1, sap, sap + 2048, sap + 4096, aq, ak, av, wave, lane);
        acc_store_bf<false>(aq, P0, wave, lane);
        acc_store_bf<false>(ak, P2, wave, lane);
        acc_store_bf<false>(av, P3, wave, lane);
    }
    __syncthreads();                                               // B3
    attn24<true>(P0, P2, P3, t);                                   // I4
    __syncthreads();                                               // B4

    // I5: out-proj + residual + LN1 -> h1 in P1 ; THEN (same interval) encconv0
    // (lnbuf=P2: K dead since B4. encconv0 reads P4/enc0, writes P3: V dead since B4.)
    f32x4 hres[2][2];
    {
        f32x4 a[2][2];
        acc_init(a, sab + 384, wave, lane);
        gemm24<4>(P0, (const us8*)(lw + 81920), 0, a, wave, lane);
        #pragma unroll
        for (int mt = 0; mt < 2; mt++)
        #pragma unroll
        for (int nt = 0; nt < 2; nt++) hres[mt][nt] = a[mt][nt] + cacc[mt][nt];
    }
    ln_inreg(hres, lnbuf, lg, lb, wave, lane);                     // internal barrier
    acc_store_bf<false>(hres, P1, wave, lane);                     // h1
    {   // encconv0 -> ES0 in P3
        const us8* ckp = (const us8*)(lw + 98304);
        f32x4 a[2][2];
        acc_init(a, ckb, wave, lane);
        gemm24_rows(P4, srp, ckp,        a, wave, lane);
        gemm24_rows(P4, srf, ckp + 2048, a, wave, lane);
        gemm24_rows(P4, srn, ckp + 4096, a, wave, lane);
        acc_store_bf<false>(a, P3, wave, lane);
    }
    __syncthreads();                                               // B5

    // ---- CROSS (2 encoders, averaged) ----
    f32x4 creg[2][2];
    #pragma unroll
    for (int nt = 0; nt < 2; nt++) {
        int col = (wave*2 + nt)*16 + (lane & 15);
        float bv = cab[3*128 + col] + cab[7*128 + col];
        #pragma unroll
        for (int mt = 0; mt < 2; mt++) { creg[mt][nt][0]=bv; creg[mt][nt][1]=bv; creg[mt][nt][2]=bv; creg[mt][nt][3]=bv; }
    }

    const us8* cap0 = (const us8*)(lw + 196608);
    {   // I6: QKV0 -- Q0<-P1 -> P0 ; K0,V0 <- ES0(P3) -> P2,P4 (enc0 consumed)
        f32x4 aq[2][2], ak[2][2], av[2][2];
        acc_init(aq, cab, wave, lane);
        gemm24<4>(P1, cap0, 0, aq, wave, lane);
        acc_store_bf<false>(aq, P0, wave, lane);
        acc_init(ak, cab + 128, wave, lane);
        acc_init(av, cab + 256, wave, lane);
        gemm24_x2(P3, cap0 + 2048, cap0 + 4096, ak, av, wave, lane);
        acc_store_bf<false>(ak, P2, wave, lane);                   // K0
        acc_store_bf<false>(av, P4, wave, lane);                   // V0
    }
    __syncthreads();                                               // B6
    stage24_bf(encb + ((size_t)BN_ + bid*2) * (S_*E_), P3, t);     // enc1 -> P3 (ES0 dead)
    attn24<false>(P0, P2, P4, t);                                  // I7
    __syncthreads();                                               // B7

    // I8 (merged): out-proj 0 (reads P0=AO0) + encconv1 (reads P3=enc1, writes P4=dead V0)
    gemm24<4>(P0, cap0 + 6144, 0, creg, wave, lane);
    {
        const us8* ckp = (const us8*)(lw + 98304 + 3*16384);
        f32x4 a[2][2];
        acc_init(a, ckb + 128, wave, lane);
        gemm24_rows(P3, srp, ckp,        a, wave, lane);
        gemm24_rows(P3, srf, ckp + 2048, a, wave, lane);
        gemm24_rows(P3, srn, ckp + 4096, a, wave, lane);
        acc_store_bf<false>(a, P4, wave, lane);                    // ES1
    }
    __syncthreads();                                               // B8

    const us8* cap1 = (const us8*)(lw + 196608 + 4*16384);
    {   // I9: QKV1 -- Q1<-P1 -> P0 (AO0 dead) ; K1,V1 <- ES1(P4) -> P2 (K0 dead), P3 (enc1 consumed)
        f32x4 aq[2][2], ak[2][2], av[2][2];
        acc_init(aq, cab + 4*128, wave, lane);
        gemm24<4>(P1, cap1, 0, aq, wave, lane);
        acc_store_bf<false>(aq, P0, wave, lane);
        acc_init(ak, cab + 5*128, wave, lane);
        acc_init(av, cab + 6*128, wave, lane);
        gemm24_x2(P4, cap1 + 2048, cap1 + 4096, ak, av, wave, lane);
        acc_store_bf<false>(ak, P2, wave, lane);                   // K1
        acc_store_bf<false>(av, P3, wave, lane);                   // V1
    }
    __syncthreads();                                               // B9
    attn24<false>(P0, P2, P3, t);                                  // I10
    __syncthreads();                                               // B10

    // I11: out-proj 1 + cross residual + LN2 + h2 store (lnbuf=P2: K1 dead since B10)
    gemm24<4>(P0, cap1 + 6144, 0, creg, wave, lane);
    #pragma unroll
    for (int mt = 0; mt < 2; mt++)
    #pragma unroll
    for (int nt = 0; nt < 2; nt++) hres[mt][nt] = hres[mt][nt] + 0.5f*creg[mt][nt];
    ln_inreg(hres, lnbuf, lg + 128, lb + 128, wave, lane);         // internal barrier
    acc_store_bf<false>(hres, P1, wave, lane);                     // h2 (FFN input)
    __syncthreads();                                               // B11

    // ---- FFN: 2 halves of 256 cols (mid half -> P2+P3, then ff2 over both) ----
    f32x4 ffacc[2][2];
    acc_init(ffacc, fb2, wave, lane);
    #pragma unroll
    for (int half = 0; half < 2; half++) {
        {
            f32x4 a[2][2];
            acc_init(a, fb1 + (half*2)*128, wave, lane);
            gemm24<4>(P1, (const us8*)(lw + 327680) + (half*2)*2048, 0, a, wave, lane);
            acc_store_bf<true>(a, P2, wave, lane);
        }
        {
            f32x4 a[2][2];
            acc_init(a, fb1 + (half*2 + 1)*128, wave, lane);
            gemm24<4>(P1, (const us8*)(lw + 327680) + (half*2 + 1)*2048, 0, a, wave, lane);
            acc_store_bf<true>(a, P3, wave, lane);
        }
        __syncthreads();                                           // B12 / B14
        gemm24<16>(P2, (const us8*)(lw + 393216), (half*2)*4,     ffacc, wave, lane);
        gemm24<16>(P3, (const us8*)(lw + 393216), (half*2 + 1)*4, ffacc, wave, lane);
        __syncthreads();                                           // B13 / B15
    }
    #pragma unroll
    for (int mt = 0; mt < 2; mt++)
    #pragma unroll
    for (int nt = 0; nt < 2; nt++) hres[mt][nt] = hres[mt][nt] + ffacc[mt][nt];
    // B15 guarantees all P2 reads complete -> lnbuf (aliasing P2) safe
    ln_inreg(hres, lnbuf, lg + 256, lb + 256, wave, lane);         // internal barrier

    if (FIN) {
        // fused final projection (OUT=1) with output transpose
        float fw[2];
        #pragma unroll
        for (int nt = 0; nt < 2; nt++) fw[nt] = fcw[(wave*2 + nt)*16 + (lane & 15)];
        float pr[2][4];
        #pragma unroll
        for (int mt = 0; mt < 2; mt++)
        #pragma unroll
        for (int r = 0; r < 4; r++) {
            float p = hres[mt][0][r]*fw[0] + hres[mt][1][r]*fw[1];
            #pragma unroll
            for (int off = 1; off < 16; off <<= 1) p += __shfl_xor(p, off);
            pr[mt][r] = p;
        }
        __syncthreads();                                           // lnbuf readers done
        if ((lane & 15) == 0) {
            #pragma unroll
            for (int mt = 0; mt < 2; mt++)
            #pragma unroll
            for (int r = 0; r < 4; r++) {
                int row = mt*16 + ((lane >> 4) << 2) + r;
                lnbuf[row*4 + wave] = pr[mt][r];
            }
        }
        __syncthreads();
        if (t < 24) {
            int g = t / 12, s = t % 12;
            int row = g*16 + s;
            float s4 = lnbuf[row*4] + lnbuf[row*4+1] + lnbuf[row*4+2] + lnbuf[row*4+3] + fcb[0];
            int bn = bid*2 + g;
            int b = bn / N_, n = bn - b*N_;
            outp[(b*S_ + s)*N_ + n] = s4;
        }
    } else {
        #pragma unroll
        for (int mt = 0; mt < 2; mt++)
        #pragma unroll
        for (int r = 0; r < 4; r++) {
            int row = ((lane >> 4) << 2) + r;
            if (row < 12) {
                #pragma unroll
                for (int nt = 0; nt < 2; nt++) {
                    int col = (wave*2 + nt)*16 + (lane & 15);
                    hp[(mt*S_ + row)*E_ + col] = f2bf(hres[mt][nt][r]);
                }
            }
        }
    }
}

extern "C" void kernel_launch(void* const* d_in, const int* in_sizes, int n_in,
                              void* d_out, int out_size, void* d_ws, size_t ws_size,
                              hipStream_t stream) {
    const float* x        = (const float*)d_in[0];
    const float* enc_x    = (const float*)d_in[1];
    const float* emb_w    = (const float*)d_in[3];
    const float* emb_b    = (const float*)d_in[4];
    const float* pe       = (const float*)d_in[5];
    const float* conv_q_w = (const float*)d_in[6];
    const float* conv_k_w = (const float*)d_in[7];
    const float* conv_k_b = (const float*)d_in[8];
    const float* sa_w     = (const float*)d_in[9];
    const float* sa_b     = (const float*)d_in[10];
    const float* ca_w     = (const float*)d_in[11];
    const float* ca_b     = (const float*)d_in[12];
    const float* ff_w1    = (const float*)d_in[13];
    const float* ff_b1    = (const float*)d_in[14];
    const float* ff_w2    = (const float*)d_in[15];
    const float* ff_b2    = (const float*)d_in[16];
    const float* ln_g     = (const float*)d_in[17];
    const float* ln_b     = (const float*)d_in[18];
    const float* fc_w     = (const float*)d_in[19];
    const float* fc_b     = (const float*)d_in[20];

    const size_t HN = (size_t)BN_ * S_ * E_;    // 16,711,680 elems
    u16* hb   = (u16*)d_ws;                     // h bf16
    u16* encb = hb + HN;                        // enc bf16 (2*HN)
    u16* wpk  = encb + 2*HN;

    {
        int n8 = (int)(2*HN/8);                 // 4,177,920
        k_encbf<<<(n8 + 255)/256, 256, 0, stream>>>(enc_x, encb, n8);
    }
    k_wpack<<<896, 256, 0, stream>>>(conv_q_w, sa_w, conv_k_w, ca_w, ff_w1, ff_w2, wpk);

    for (int l = 0; l < L_; l++) {
        const u16* lw = wpk + (size_t)l*458752;
        const float* sab = sa_b + l*512;
        const float* ckb = conv_k_b + l*256;
        const float* cab = ca_b + l*1024;
        const float* fb1 = ff_b1 + l*512;
        const float* fb2 = ff_b2 + l*128;
        const float* lg  = ln_g + l*384;
        const float* lb  = ln_b + l*384;
        if (l == 0)
            k_layer<true, false><<<BN_/2, THREADS, 0, stream>>>(hb, x, emb_w, emb_b, pe, encb, lw,
                sab, ckb, cab, fb1, fb2, lg, lb, fc_w, fc_b, (float*)d_out);
        else if (l == L_-1)
            k_layer<false, true><<<BN_/2, THREADS, 0, stream>>>(hb, x, emb_w, emb_b, pe, encb, lw,
                sab, ckb, cab, fb1, fb2, lg, lb, fc_w, fc_b, (float*)d_out);
        else
            k_layer<false, false><<<BN_/2, THREADS, 0, stream>>>(hb, x, emb_w, emb_b, pe, encb, lw,
                sab, ckb, cab, fb1, fb2, lg, lb, fc_w, fc_b, (float*)d_out);
    }
}